// Round 2
// baseline (52.954 us; speedup 1.0000x reference)
//
#include <hip/hip_runtime.h>
#include <hip/hip_bf16.h>

#define IN_FEATS 128
#define HIDDEN 32

// Kernel 1: p[n][j] = sum_k h[n][k] * W1[k][j]   (n < n_nodes, j < 32)
// Block = 256 threads = 8 rows x 32 cols. W1 (16 KB) + 8 h-rows (4 KB) staged in LDS.
__global__ __launch_bounds__(256) void node_proj_kernel(
    const float* __restrict__ h,
    const float* __restrict__ W1,
    float* __restrict__ p,
    int n_nodes) {
    __shared__ float W1s[IN_FEATS * HIDDEN];   // 16 KB = 4096 floats = 1024 float4
    __shared__ float hs[8 * IN_FEATS];         // 4 KB

    const int t = threadIdx.x;

    // Stage W1: 4096 floats = 1024 float4s -> each of 256 threads loads 4.
    {
        const float4* W1v = (const float4*)W1;
        float4* W1sv = (float4*)W1s;
#pragma unroll
        for (int i = 0; i < 4; ++i) {
            W1sv[t + i * 256] = W1v[t + i * 256];
        }
    }

    const int row0 = blockIdx.x * 8;

    // Stage 8 rows of h: 1024 floats = 256 float4s (coalesced)
    {
        const int r = t >> 5;          // which of the 8 rows
        const int c4 = t & 31;         // which float4 within the row (32 x 4 = 128)
        if (row0 + r < n_nodes) {
            const float4* hv = (const float4*)(h + (size_t)(row0 + r) * IN_FEATS);
            float4* hsv = (float4*)(hs + r * IN_FEATS);
            hsv[c4] = hv[c4];
        }
    }
    __syncthreads();

    const int row = t >> 5;   // 0..7
    const int col = t & 31;   // 0..31
    const int grow = row0 + row;
    if (grow >= n_nodes) return;

    float acc = 0.0f;
    const float* hrow = hs + row * IN_FEATS;
#pragma unroll
    for (int k = 0; k < IN_FEATS; ++k) {
        // hs read: broadcast within the 32-lane col-group. W1s: 32 consecutive banks.
        acc = fmaf(hrow[k], W1s[k * HIDDEN + col], acc);
    }
    p[(size_t)grow * HIDDEN + col] = acc;   // coalesced
}

// Kernel 2: per edge e: out[e] = relu(p[src[e]] + p[dst[e]] + b1) . W2 + b2
__global__ __launch_bounds__(256) void edge_mlp_kernel(
    const float* __restrict__ p,
    const int* __restrict__ src,
    const int* __restrict__ dst,
    const float* __restrict__ b1,
    const float* __restrict__ W2,
    const float* __restrict__ b2,
    float* __restrict__ out,
    int n_edges) {
    __shared__ float b1s[HIDDEN];
    __shared__ float w2s[HIDDEN];
    __shared__ float b2s;

    const int t = threadIdx.x;
    if (t < HIDDEN) {
        b1s[t] = b1[t];
        w2s[t] = W2[t];
    }
    if (t == 0) b2s = b2[0];
    __syncthreads();

    const int e = blockIdx.x * 256 + t;
    if (e >= n_edges) return;

    const int s = src[e];
    const int d = dst[e];

    const float4* ps = (const float4*)(p + (size_t)s * HIDDEN);
    const float4* pd = (const float4*)(p + (size_t)d * HIDDEN);

    float acc = 0.0f;
#pragma unroll
    for (int j4 = 0; j4 < HIDDEN / 4; ++j4) {
        const float4 a = ps[j4];
        const float4 b = pd[j4];
        const int j = j4 * 4;
        float v0 = fmaxf(a.x + b.x + b1s[j + 0], 0.0f);
        float v1 = fmaxf(a.y + b.y + b1s[j + 1], 0.0f);
        float v2 = fmaxf(a.z + b.z + b1s[j + 2], 0.0f);
        float v3 = fmaxf(a.w + b.w + b1s[j + 3], 0.0f);
        acc = fmaf(v0, w2s[j + 0], acc);
        acc = fmaf(v1, w2s[j + 1], acc);
        acc = fmaf(v2, w2s[j + 2], acc);
        acc = fmaf(v3, w2s[j + 3], acc);
    }
    out[e] = acc + b2s;   // coalesced store
}

// Fallback (used only if ws_size is too small for p): fully fused, one wave-half
// (32 threads) per edge, correct but slower. Block = 256 = 8 edges.
__global__ __launch_bounds__(256) void fused_edge_kernel(
    const float* __restrict__ h,
    const int* __restrict__ src,
    const int* __restrict__ dst,
    const float* __restrict__ W1,
    const float* __restrict__ b1,
    const float* __restrict__ W2,
    const float* __restrict__ b2,
    float* __restrict__ out,
    int n_edges) {
    __shared__ float W1s[IN_FEATS * HIDDEN];
    __shared__ float sc[8][IN_FEATS];

    const int t = threadIdx.x;
    {
        const float4* W1v = (const float4*)W1;
        float4* W1sv = (float4*)W1s;
#pragma unroll
        for (int i = 0; i < 4; ++i) W1sv[t + i * 256] = W1v[t + i * 256];
    }

    const int le = t >> 5;    // 0..7 local edge
    const int j  = t & 31;    // hidden unit / lane-in-group
    const int e = blockIdx.x * 8 + le;
    __syncthreads();

    if (e < n_edges) {
        const int s = src[e];
        const int d = dst[e];
        const float4* hs4 = (const float4*)(h + (size_t)s * IN_FEATS);
        const float4* hd4 = (const float4*)(h + (size_t)d * IN_FEATS);
        float4* sc4 = (float4*)sc[le];
        float4 a = hs4[j], b = hd4[j];
        sc4[j] = make_float4(a.x + b.x, a.y + b.y, a.z + b.z, a.w + b.w);
    }
    __syncthreads();

    if (e >= n_edges) return;

    float acc = b1[j];
    const float* scp = sc[le];
#pragma unroll
    for (int k = 0; k < IN_FEATS; ++k)
        acc = fmaf(scp[k], W1s[k * HIDDEN + j], acc);
    float hval = fmaxf(acc, 0.0f) * W2[j];

    // reduce 32 values within the half-wave (lanes le*32 .. le*32+31)
#pragma unroll
    for (int off = 16; off >= 1; off >>= 1)
        hval += __shfl_down(hval, off, 32);

    if (j == 0) out[e] = hval + b2[0];
}

extern "C" void kernel_launch(void* const* d_in, const int* in_sizes, int n_in,
                              void* d_out, int out_size, void* d_ws, size_t ws_size,
                              hipStream_t stream) {
    // setup_inputs() order: h, src, dst, W1, b1, W2, b2
    const float* h   = (const float*)d_in[0];
    const int*   src = (const int*)d_in[1];
    const int*   dst = (const int*)d_in[2];
    const float* W1  = (const float*)d_in[3];
    const float* b1  = (const float*)d_in[4];
    const float* W2  = (const float*)d_in[5];
    const float* b2  = (const float*)d_in[6];
    float* out = (float*)d_out;

    const int n_nodes = in_sizes[0] / IN_FEATS;   // 40000
    const int n_edges = in_sizes[1];              // 640000

    const size_t p_bytes = (size_t)n_nodes * HIDDEN * sizeof(float);  // 5.12 MB

    if (ws_size >= p_bytes) {
        float* p = (float*)d_ws;
        node_proj_kernel<<<(n_nodes + 7) / 8, 256, 0, stream>>>(h, W1, p, n_nodes);
        edge_mlp_kernel<<<(n_edges + 255) / 256, 256, 0, stream>>>(
            p, src, dst, b1, W2, b2, out, n_edges);
    } else {
        fused_edge_kernel<<<(n_edges + 7) / 8, 256, 0, stream>>>(
            h, src, dst, W1, b1, W2, b2, out, n_edges);
    }
}

// Round 3
// 42.547 us; speedup vs baseline: 1.2446x; 1.2446x over previous
//
#include <hip/hip_runtime.h>
#include <hip/hip_bf16.h>

#define IN_FEATS 128
#define HIDDEN 32

typedef __attribute__((ext_vector_type(8))) short bf16x8;   // 8 bf16 (4 VGPRs)
typedef __attribute__((ext_vector_type(4))) float f32x4;

// fp32 -> bf16 round-to-nearest-even (bit trick; NaN irrelevant for this data)
static __device__ __forceinline__ short f2bf(float f) {
    union { float f; unsigned u; } v;
    v.f = f;
    unsigned r = v.u + 0x7FFFu + ((v.u >> 16) & 1u);
    return (short)(r >> 16);
}

// Kernel 1 (MFMA): p = h @ W1  [40000x128 @ 128x32]
// 1 wave per 16-row tile, 4 waves/block, no LDS.
// Verified gfx950 16x16x32 bf16 layouts (learn_hip m89/m91):
//   A-frag: lane holds A[m=lane&15][k = (lane>>4)*8 + i], i=0..7
//   B-frag: lane holds B[k = (lane>>4)*8 + i][n=lane&15]
//   D:      lane holds D[row=(lane>>4)*4 + r][col=lane&15], r=0..3
__global__ __launch_bounds__(256) void node_proj_mfma(
    const float* __restrict__ h,
    const float* __restrict__ W1,
    float* __restrict__ p,
    int n_nodes) {
    const int t = threadIdx.x;
    const int lane = t & 63;
    const int wave = t >> 6;
    const int tile = blockIdx.x * 4 + wave;     // 16-row output tile
    const int row0 = tile * 16;
    if (row0 >= n_nodes) return;                // 40000 % 16 == 0: whole tiles only

    const int lr = lane & 15;                   // 16-dim index (m for A, n for B/D-col)
    const int kg = lane >> 4;                   // k-group 0..3

    // B fragments from W1 (row-major [K=128][N=32]): 16 KB, L1/L2-resident.
    // b[ct][ks][i] = W1[(ks*32 + kg*8 + i)][ct*16 + lr]
    bf16x8 bfrag[2][4];
#pragma unroll
    for (int ct = 0; ct < 2; ++ct) {
#pragma unroll
        for (int ks = 0; ks < 4; ++ks) {
            const float* wp = W1 + (size_t)(ks * 32 + kg * 8) * HIDDEN + ct * 16 + lr;
#pragma unroll
            for (int i = 0; i < 8; ++i)
                bfrag[ct][ks][i] = f2bf(wp[(size_t)i * HIDDEN]);
        }
    }

    // A fragments from h (row-major [N][128]); 8 consecutive floats per kstep = 2 float4.
    const float* hrow = h + (size_t)(row0 + lr) * IN_FEATS + kg * 8;
    bf16x8 afrag[4];
#pragma unroll
    for (int ks = 0; ks < 4; ++ks) {
        const float4 v0 = *(const float4*)(hrow + ks * 32);
        const float4 v1 = *(const float4*)(hrow + ks * 32 + 4);
        afrag[ks][0] = f2bf(v0.x);
        afrag[ks][1] = f2bf(v0.y);
        afrag[ks][2] = f2bf(v0.z);
        afrag[ks][3] = f2bf(v0.w);
        afrag[ks][4] = f2bf(v1.x);
        afrag[ks][5] = f2bf(v1.y);
        afrag[ks][6] = f2bf(v1.z);
        afrag[ks][7] = f2bf(v1.w);
    }

    f32x4 acc0 = {0.f, 0.f, 0.f, 0.f};
    f32x4 acc1 = {0.f, 0.f, 0.f, 0.f};
#pragma unroll
    for (int ks = 0; ks < 4; ++ks) {
        acc0 = __builtin_amdgcn_mfma_f32_16x16x32_bf16(afrag[ks], bfrag[0][ks], acc0, 0, 0, 0);
        acc1 = __builtin_amdgcn_mfma_f32_16x16x32_bf16(afrag[ks], bfrag[1][ks], acc1, 0, 0, 0);
    }

    // Store: D[row=(kg*4+r)][col=ct*16+lr]
    float* prow = p + (size_t)row0 * HIDDEN;
#pragma unroll
    for (int r = 0; r < 4; ++r) {
        prow[(size_t)(kg * 4 + r) * HIDDEN + lr]      = acc0[r];
        prow[(size_t)(kg * 4 + r) * HIDDEN + 16 + lr] = acc1[r];
    }
}

// Kernel 2: per edge e: out[e] = relu(p[src[e]] + p[dst[e]] + b1) . W2 + b2
__global__ __launch_bounds__(256) void edge_mlp_kernel(
    const float* __restrict__ p,
    const int* __restrict__ src,
    const int* __restrict__ dst,
    const float* __restrict__ b1,
    const float* __restrict__ W2,
    const float* __restrict__ b2,
    float* __restrict__ out,
    int n_edges) {
    __shared__ float b1s[HIDDEN];
    __shared__ float w2s[HIDDEN];
    __shared__ float b2s;

    const int t = threadIdx.x;
    if (t < HIDDEN) {
        b1s[t] = b1[t];
        w2s[t] = W2[t];
    }
    if (t == 0) b2s = b2[0];
    __syncthreads();

    const int e = blockIdx.x * 256 + t;
    if (e >= n_edges) return;

    const int s = src[e];
    const int d = dst[e];

    const float4* ps = (const float4*)(p + (size_t)s * HIDDEN);
    const float4* pd = (const float4*)(p + (size_t)d * HIDDEN);

    float acc = 0.0f;
#pragma unroll
    for (int j4 = 0; j4 < HIDDEN / 4; ++j4) {
        const float4 a = ps[j4];
        const float4 b = pd[j4];
        const int j = j4 * 4;
        float v0 = fmaxf(a.x + b.x + b1s[j + 0], 0.0f);
        float v1 = fmaxf(a.y + b.y + b1s[j + 1], 0.0f);
        float v2 = fmaxf(a.z + b.z + b1s[j + 2], 0.0f);
        float v3 = fmaxf(a.w + b.w + b1s[j + 3], 0.0f);
        acc = fmaf(v0, w2s[j + 0], acc);
        acc = fmaf(v1, w2s[j + 1], acc);
        acc = fmaf(v2, w2s[j + 2], acc);
        acc = fmaf(v3, w2s[j + 3], acc);
    }
    out[e] = acc + b2s;   // coalesced store
}

// Fallback (only if ws too small for p): fused, correct, slower.
__global__ __launch_bounds__(256) void fused_edge_kernel(
    const float* __restrict__ h,
    const int* __restrict__ src,
    const int* __restrict__ dst,
    const float* __restrict__ W1,
    const float* __restrict__ b1,
    const float* __restrict__ W2,
    const float* __restrict__ b2,
    float* __restrict__ out,
    int n_edges) {
    __shared__ float W1s[IN_FEATS * HIDDEN];
    __shared__ float sc[8][IN_FEATS];

    const int t = threadIdx.x;
    {
        const float4* W1v = (const float4*)W1;
        float4* W1sv = (float4*)W1s;
#pragma unroll
        for (int i = 0; i < 4; ++i) W1sv[t + i * 256] = W1v[t + i * 256];
    }

    const int le = t >> 5;
    const int j  = t & 31;
    const int e = blockIdx.x * 8 + le;
    __syncthreads();

    if (e < n_edges) {
        const int s = src[e];
        const int d = dst[e];
        const float4* hs4 = (const float4*)(h + (size_t)s * IN_FEATS);
        const float4* hd4 = (const float4*)(h + (size_t)d * IN_FEATS);
        float4* sc4 = (float4*)sc[le];
        float4 a = hs4[j], b = hd4[j];
        sc4[j] = make_float4(a.x + b.x, a.y + b.y, a.z + b.z, a.w + b.w);
    }
    __syncthreads();

    if (e >= n_edges) return;

    float acc = b1[j];
    const float* scp = sc[le];
#pragma unroll
    for (int k = 0; k < IN_FEATS; ++k)
        acc = fmaf(scp[k], W1s[k * HIDDEN + j], acc);
    float hval = fmaxf(acc, 0.0f) * W2[j];

#pragma unroll
    for (int off = 16; off >= 1; off >>= 1)
        hval += __shfl_down(hval, off, 32);

    if (j == 0) out[e] = hval + b2[0];
}

extern "C" void kernel_launch(void* const* d_in, const int* in_sizes, int n_in,
                              void* d_out, int out_size, void* d_ws, size_t ws_size,
                              hipStream_t stream) {
    // setup_inputs() order: h, src, dst, W1, b1, W2, b2
    const float* h   = (const float*)d_in[0];
    const int*   src = (const int*)d_in[1];
    const int*   dst = (const int*)d_in[2];
    const float* W1  = (const float*)d_in[3];
    const float* b1  = (const float*)d_in[4];
    const float* W2  = (const float*)d_in[5];
    const float* b2  = (const float*)d_in[6];
    float* out = (float*)d_out;

    const int n_nodes = in_sizes[0] / IN_FEATS;   // 40000
    const int n_edges = in_sizes[1];              // 640000

    const size_t p_bytes = (size_t)n_nodes * HIDDEN * sizeof(float);  // 5.12 MB

    if (ws_size >= p_bytes) {
        float* p = (float*)d_ws;
        const int tiles = (n_nodes + 15) / 16;        // 2500
        node_proj_mfma<<<(tiles + 3) / 4, 256, 0, stream>>>(h, W1, p, n_nodes);
        edge_mlp_kernel<<<(n_edges + 255) / 256, 256, 0, stream>>>(
            p, src, dst, b1, W2, b2, out, n_edges);
    } else {
        fused_edge_kernel<<<(n_edges + 7) / 8, 256, 0, stream>>>(
            h, src, dst, W1, b1, W2, b2, out, n_edges);
    }
}

// Round 4
// 30.321 us; speedup vs baseline: 1.7464x; 1.4032x over previous
//
#include <hip/hip_runtime.h>
#include <hip/hip_bf16.h>

#define IN_FEATS 128
#define HIDDEN 32

typedef __attribute__((ext_vector_type(8))) short bf16x8;   // 8 bf16 (4 VGPRs)
typedef __attribute__((ext_vector_type(4))) float f32x4;

// fp32 -> bf16 round-to-nearest-even (bit trick; NaN irrelevant for this data)
static __device__ __forceinline__ short f2bf(float f) {
    union { float f; unsigned u; } v;
    v.f = f;
    unsigned r = v.u + 0x7FFFu + ((v.u >> 16) & 1u);
    return (short)(r >> 16);
}

// Kernel 1 (MFMA): p = h @ W1  [40000x128 @ 128x32]
// 1 wave per 16-row tile, 4 waves/block, no LDS.
// Verified gfx950 16x16x32 bf16 layouts (learn_hip m89/m91):
//   A-frag: lane holds A[m=lane&15][k = (lane>>4)*8 + i], i=0..7
//   B-frag: lane holds B[k = (lane>>4)*8 + i][n=lane&15]
//   D:      lane holds D[row=(lane>>4)*4 + r][col=lane&15], r=0..3
__global__ __launch_bounds__(256) void node_proj_mfma(
    const float* __restrict__ h,
    const float* __restrict__ W1,
    float* __restrict__ p,
    int n_nodes) {
    const int t = threadIdx.x;
    const int lane = t & 63;
    const int wave = t >> 6;
    const int tile = blockIdx.x * 4 + wave;     // 16-row output tile
    const int row0 = tile * 16;
    if (row0 >= n_nodes) return;                // 40000 % 16 == 0: whole tiles only

    const int lr = lane & 15;                   // 16-dim index (m for A, n for B/D-col)
    const int kg = lane >> 4;                   // k-group 0..3

    // B fragments from W1 (row-major [K=128][N=32]): 16 KB, L1/L2-resident.
    bf16x8 bfrag[2][4];
#pragma unroll
    for (int ct = 0; ct < 2; ++ct) {
#pragma unroll
        for (int ks = 0; ks < 4; ++ks) {
            const float* wp = W1 + (size_t)(ks * 32 + kg * 8) * HIDDEN + ct * 16 + lr;
#pragma unroll
            for (int i = 0; i < 8; ++i)
                bfrag[ct][ks][i] = f2bf(wp[(size_t)i * HIDDEN]);
        }
    }

    // A fragments from h (row-major [N][128]); 8 consecutive floats per kstep = 2 float4.
    const float* hrow = h + (size_t)(row0 + lr) * IN_FEATS + kg * 8;
    bf16x8 afrag[4];
#pragma unroll
    for (int ks = 0; ks < 4; ++ks) {
        const float4 v0 = *(const float4*)(hrow + ks * 32);
        const float4 v1 = *(const float4*)(hrow + ks * 32 + 4);
        afrag[ks][0] = f2bf(v0.x);
        afrag[ks][1] = f2bf(v0.y);
        afrag[ks][2] = f2bf(v0.z);
        afrag[ks][3] = f2bf(v0.w);
        afrag[ks][4] = f2bf(v1.x);
        afrag[ks][5] = f2bf(v1.y);
        afrag[ks][6] = f2bf(v1.z);
        afrag[ks][7] = f2bf(v1.w);
    }

    f32x4 acc0 = {0.f, 0.f, 0.f, 0.f};
    f32x4 acc1 = {0.f, 0.f, 0.f, 0.f};
#pragma unroll
    for (int ks = 0; ks < 4; ++ks) {
        acc0 = __builtin_amdgcn_mfma_f32_16x16x32_bf16(afrag[ks], bfrag[0][ks], acc0, 0, 0, 0);
        acc1 = __builtin_amdgcn_mfma_f32_16x16x32_bf16(afrag[ks], bfrag[1][ks], acc1, 0, 0, 0);
    }

    // Store: D[row=(kg*4+r)][col=ct*16+lr]
    float* prow = p + (size_t)row0 * HIDDEN;
#pragma unroll
    for (int r = 0; r < 4; ++r) {
        prow[(size_t)(kg * 4 + r) * HIDDEN + lr]      = acc0[r];
        prow[(size_t)(kg * 4 + r) * HIDDEN + 16 + lr] = acc1[r];
    }
}

// Kernel 2 (cooperative gather): 8 lanes per edge.
// Lane q of an edge-group loads float4 #q of the src row and of the dst row:
// one wave-wide load instruction covers 8 edges -> 16 cache lines (vs 64 for
// the one-thread-per-edge layout). Hidden units j = q*4..q*4+3 per lane;
// 3-step __shfl_xor reduce within the 8-lane group.
__global__ __launch_bounds__(256) void edge_mlp_coop(
    const float* __restrict__ p,
    const int* __restrict__ src,
    const int* __restrict__ dst,
    const float* __restrict__ b1,
    const float* __restrict__ W2,
    const float* __restrict__ b2,
    float* __restrict__ out,
    int n_edges) {
    const int t = threadIdx.x;
    const int q = t & 7;          // float4 slot within the row
    const int slot = t >> 3;      // edge slot within block (0..31)

    // Per-thread constant slices (L1-broadcast loads)
    const float4 b1v = ((const float4*)b1)[q];
    const float4 w2v = ((const float4*)W2)[q];
    const float b2s = b2[0];

    const int base = blockIdx.x * 128;   // 4 edges per slot per block

#pragma unroll
    for (int it = 0; it < 4; ++it) {
        const int e = base + it * 32 + slot;
        if (e >= n_edges) return;

        const int s = src[e];   // 8 lanes same address: broadcast
        const int d = dst[e];

        const float4 a = ((const float4*)(p + (size_t)s * HIDDEN))[q];
        const float4 b = ((const float4*)(p + (size_t)d * HIDDEN))[q];

        float v0 = fmaxf(a.x + b.x + b1v.x, 0.0f);
        float v1 = fmaxf(a.y + b.y + b1v.y, 0.0f);
        float v2 = fmaxf(a.z + b.z + b1v.z, 0.0f);
        float v3 = fmaxf(a.w + b.w + b1v.w, 0.0f);

        float part = v0 * w2v.x;
        part = fmaf(v1, w2v.y, part);
        part = fmaf(v2, w2v.z, part);
        part = fmaf(v3, w2v.w, part);

        // reduce across the 8-lane group
        part += __shfl_xor(part, 1, 8);
        part += __shfl_xor(part, 2, 8);
        part += __shfl_xor(part, 4, 8);

        if (q == 0) out[e] = part + b2s;
    }
}

// Fallback (only if ws too small for p): fused, correct, slower.
__global__ __launch_bounds__(256) void fused_edge_kernel(
    const float* __restrict__ h,
    const int* __restrict__ src,
    const int* __restrict__ dst,
    const float* __restrict__ W1,
    const float* __restrict__ b1,
    const float* __restrict__ W2,
    const float* __restrict__ b2,
    float* __restrict__ out,
    int n_edges) {
    __shared__ float W1s[IN_FEATS * HIDDEN];
    __shared__ float sc[8][IN_FEATS];

    const int t = threadIdx.x;
    {
        const float4* W1v = (const float4*)W1;
        float4* W1sv = (float4*)W1s;
#pragma unroll
        for (int i = 0; i < 4; ++i) W1sv[t + i * 256] = W1v[t + i * 256];
    }

    const int le = t >> 5;
    const int j  = t & 31;
    const int e = blockIdx.x * 8 + le;
    __syncthreads();

    if (e < n_edges) {
        const int s = src[e];
        const int d = dst[e];
        const float4* hs4 = (const float4*)(h + (size_t)s * IN_FEATS);
        const float4* hd4 = (const float4*)(h + (size_t)d * IN_FEATS);
        float4* sc4 = (float4*)sc[le];
        float4 a = hs4[j], b = hd4[j];
        sc4[j] = make_float4(a.x + b.x, a.y + b.y, a.z + b.z, a.w + b.w);
    }
    __syncthreads();

    if (e >= n_edges) return;

    float acc = b1[j];
    const float* scp = sc[le];
#pragma unroll
    for (int k = 0; k < IN_FEATS; ++k)
        acc = fmaf(scp[k], W1s[k * HIDDEN + j], acc);
    float hval = fmaxf(acc, 0.0f) * W2[j];

#pragma unroll
    for (int off = 16; off >= 1; off >>= 1)
        hval += __shfl_down(hval, off, 32);

    if (j == 0) out[e] = hval + b2[0];
}

extern "C" void kernel_launch(void* const* d_in, const int* in_sizes, int n_in,
                              void* d_out, int out_size, void* d_ws, size_t ws_size,
                              hipStream_t stream) {
    // setup_inputs() order: h, src, dst, W1, b1, W2, b2
    const float* h   = (const float*)d_in[0];
    const int*   src = (const int*)d_in[1];
    const int*   dst = (const int*)d_in[2];
    const float* W1  = (const float*)d_in[3];
    const float* b1  = (const float*)d_in[4];
    const float* W2  = (const float*)d_in[5];
    const float* b2  = (const float*)d_in[6];
    float* out = (float*)d_out;

    const int n_nodes = in_sizes[0] / IN_FEATS;   // 40000
    const int n_edges = in_sizes[1];              // 640000

    const size_t p_bytes = (size_t)n_nodes * HIDDEN * sizeof(float);  // 5.12 MB

    if (ws_size >= p_bytes) {
        float* p = (float*)d_ws;
        const int tiles = (n_nodes + 15) / 16;        // 2500
        node_proj_mfma<<<(tiles + 3) / 4, 256, 0, stream>>>(h, W1, p, n_nodes);
        edge_mlp_coop<<<(n_edges + 127) / 128, 256, 0, stream>>>(
            p, src, dst, b1, W2, b2, out, n_edges);
    } else {
        fused_edge_kernel<<<(n_edges + 7) / 8, 256, 0, stream>>>(
            h, src, dst, W1, b1, W2, b2, out, n_edges);
    }
}

// Round 5
// 23.446 us; speedup vs baseline: 2.2585x; 1.2932x over previous
//
#include <hip/hip_runtime.h>
#include <hip/hip_bf16.h>

#define IN_FEATS 128
#define HIDDEN 32

typedef __attribute__((ext_vector_type(8))) short bf16x8;   // 8 bf16 (4 VGPRs)
typedef __attribute__((ext_vector_type(4))) float f32x4;
typedef __attribute__((ext_vector_type(4))) unsigned short u16x4;

// fp32 -> bf16 round-to-nearest-even (bit trick; NaN irrelevant for this data)
static __device__ __forceinline__ unsigned short f2bf(float f) {
    union { float f; unsigned u; } v;
    v.f = f;
    unsigned r = v.u + 0x7FFFu + ((v.u >> 16) & 1u);
    return (unsigned short)(r >> 16);
}

static __device__ __forceinline__ float bf2f(unsigned short u) {
    union { unsigned u; float f; } v;
    v.u = ((unsigned)u) << 16;
    return v.f;
}

// Kernel 1 (MFMA): p[n] = bf16( h[n] @ W1 + 0.5*b1 )   [40000x128 @ 128x32]
// (b1 folded in half per endpoint: p[src]+p[dst] carries the full +b1.)
// 1 wave per 16-row tile, 4 waves/block, no LDS.
// Verified gfx950 16x16x32 bf16 layouts (learn_hip m89/m91):
//   A-frag: lane holds A[m=lane&15][k=(lane>>4)*8+i]; B-frag: B[k][n=lane&15]
//   D: lane holds D[row=(lane>>4)*4+r][col=lane&15]
__global__ __launch_bounds__(256) void node_proj_mfma(
    const float* __restrict__ h,
    const float* __restrict__ W1,
    const float* __restrict__ b1,
    unsigned short* __restrict__ p,    // bf16 out
    int n_nodes) {
    const int t = threadIdx.x;
    const int lane = t & 63;
    const int wave = t >> 6;
    const int tile = blockIdx.x * 4 + wave;
    const int row0 = tile * 16;
    if (row0 >= n_nodes) return;

    const int lr = lane & 15;
    const int kg = lane >> 4;

    // B fragments from W1 (row-major [128][32]): 16 KB, L1/L2-resident.
    bf16x8 bfrag[2][4];
#pragma unroll
    for (int ct = 0; ct < 2; ++ct) {
#pragma unroll
        for (int ks = 0; ks < 4; ++ks) {
            const float* wp = W1 + (size_t)(ks * 32 + kg * 8) * HIDDEN + ct * 16 + lr;
#pragma unroll
            for (int i = 0; i < 8; ++i)
                bfrag[ct][ks][i] = (short)f2bf(wp[(size_t)i * HIDDEN]);
        }
    }

    // A fragments from h; 8 consecutive floats per kstep = 2 float4.
    const float* hrow = h + (size_t)(row0 + lr) * IN_FEATS + kg * 8;
    bf16x8 afrag[4];
#pragma unroll
    for (int ks = 0; ks < 4; ++ks) {
        const float4 v0 = *(const float4*)(hrow + ks * 32);
        const float4 v1 = *(const float4*)(hrow + ks * 32 + 4);
        afrag[ks][0] = (short)f2bf(v0.x);
        afrag[ks][1] = (short)f2bf(v0.y);
        afrag[ks][2] = (short)f2bf(v0.z);
        afrag[ks][3] = (short)f2bf(v0.w);
        afrag[ks][4] = (short)f2bf(v1.x);
        afrag[ks][5] = (short)f2bf(v1.y);
        afrag[ks][6] = (short)f2bf(v1.z);
        afrag[ks][7] = (short)f2bf(v1.w);
    }

    // init acc with 0.5*b1[col] so the bias rides through the MFMA C-operand
    const float hb0 = 0.5f * b1[lr];
    const float hb1 = 0.5f * b1[16 + lr];
    f32x4 acc0 = {hb0, hb0, hb0, hb0};
    f32x4 acc1 = {hb1, hb1, hb1, hb1};
#pragma unroll
    for (int ks = 0; ks < 4; ++ks) {
        acc0 = __builtin_amdgcn_mfma_f32_16x16x32_bf16(afrag[ks], bfrag[0][ks], acc0, 0, 0, 0);
        acc1 = __builtin_amdgcn_mfma_f32_16x16x32_bf16(afrag[ks], bfrag[1][ks], acc1, 0, 0, 0);
    }

    // Store bf16: D[row=(kg*4+r)][col=ct*16+lr]
    unsigned short* prow = p + (size_t)row0 * HIDDEN;
#pragma unroll
    for (int r = 0; r < 4; ++r) {
        prow[(size_t)(kg * 4 + r) * HIDDEN + lr]      = f2bf(acc0[r]);
        prow[(size_t)(kg * 4 + r) * HIDDEN + 16 + lr] = f2bf(acc1[r]);
    }
}

// Kernel 2: 8 lanes per edge-group, 4 CONSECUTIVE edges per slot.
// bf16 p rows are 64 B = 1 cache line -> 2 line-transactions per edge.
// All 8 row-gathers issue independently before any compute (latency hiding).
__global__ __launch_bounds__(256) void edge_mlp_coop(
    const unsigned short* __restrict__ p,   // bf16 [n_nodes][32], includes +b1/2
    const int* __restrict__ src,
    const int* __restrict__ dst,
    const float* __restrict__ W2,
    const float* __restrict__ b2,
    float* __restrict__ out,
    int n_edges) {
    const int t = threadIdx.x;
    const int q = t & 7;          // 4-elem slot within the 32-elem row
    const int slot = t >> 3;      // edge-group within block (0..31)

    const float4 w2v = ((const float4*)W2)[q];
    const float b2s = b2[0];

    const int e0 = (blockIdx.x * 32 + slot) * 4;
    if (e0 >= n_edges) return;

    float res[4];

    if (e0 + 3 < n_edges) {
        const int4 s4 = *(const int4*)(src + e0);   // broadcast within group
        const int4 d4 = *(const int4*)(dst + e0);

        // 8 independent 8-byte gathers
        const u16x4 a0 = *(const u16x4*)(p + (size_t)s4.x * HIDDEN + q * 4);
        const u16x4 a1 = *(const u16x4*)(p + (size_t)s4.y * HIDDEN + q * 4);
        const u16x4 a2 = *(const u16x4*)(p + (size_t)s4.z * HIDDEN + q * 4);
        const u16x4 a3 = *(const u16x4*)(p + (size_t)s4.w * HIDDEN + q * 4);
        const u16x4 c0 = *(const u16x4*)(p + (size_t)d4.x * HIDDEN + q * 4);
        const u16x4 c1 = *(const u16x4*)(p + (size_t)d4.y * HIDDEN + q * 4);
        const u16x4 c2 = *(const u16x4*)(p + (size_t)d4.z * HIDDEN + q * 4);
        const u16x4 c3 = *(const u16x4*)(p + (size_t)d4.w * HIDDEN + q * 4);

        const u16x4 A[4] = {a0, a1, a2, a3};
        const u16x4 C[4] = {c0, c1, c2, c3};

#pragma unroll
        for (int i = 0; i < 4; ++i) {
            float v0 = fmaxf(bf2f(A[i][0]) + bf2f(C[i][0]), 0.0f);
            float v1 = fmaxf(bf2f(A[i][1]) + bf2f(C[i][1]), 0.0f);
            float v2 = fmaxf(bf2f(A[i][2]) + bf2f(C[i][2]), 0.0f);
            float v3 = fmaxf(bf2f(A[i][3]) + bf2f(C[i][3]), 0.0f);
            float part = v0 * w2v.x;
            part = fmaf(v1, w2v.y, part);
            part = fmaf(v2, w2v.z, part);
            part = fmaf(v3, w2v.w, part);
            part += __shfl_xor(part, 1, 8);
            part += __shfl_xor(part, 2, 8);
            part += __shfl_xor(part, 4, 8);
            res[i] = part + b2s;
        }

        if (q == 0) {
            *(float4*)(out + e0) = make_float4(res[0], res[1], res[2], res[3]);
        }
    } else {
        // scalar tail (not hit for 640000 edges, kept for generality)
        for (int i = 0; i < 4 && e0 + i < n_edges; ++i) {
            const int s = src[e0 + i];
            const int d = dst[e0 + i];
            const u16x4 a = *(const u16x4*)(p + (size_t)s * HIDDEN + q * 4);
            const u16x4 c = *(const u16x4*)(p + (size_t)d * HIDDEN + q * 4);
            float v0 = fmaxf(bf2f(a[0]) + bf2f(c[0]), 0.0f);
            float v1 = fmaxf(bf2f(a[1]) + bf2f(c[1]), 0.0f);
            float v2 = fmaxf(bf2f(a[2]) + bf2f(c[2]), 0.0f);
            float v3 = fmaxf(bf2f(a[3]) + bf2f(c[3]), 0.0f);
            float part = v0 * w2v.x;
            part = fmaf(v1, w2v.y, part);
            part = fmaf(v2, w2v.z, part);
            part = fmaf(v3, w2v.w, part);
            part += __shfl_xor(part, 1, 8);
            part += __shfl_xor(part, 2, 8);
            part += __shfl_xor(part, 4, 8);
            if (q == 0) out[e0 + i] = part + b2s;
        }
    }
}

// Fallback (only if ws too small for p): fused, correct, slower.
__global__ __launch_bounds__(256) void fused_edge_kernel(
    const float* __restrict__ h,
    const int* __restrict__ src,
    const int* __restrict__ dst,
    const float* __restrict__ W1,
    const float* __restrict__ b1,
    const float* __restrict__ W2,
    const float* __restrict__ b2,
    float* __restrict__ out,
    int n_edges) {
    __shared__ float W1s[IN_FEATS * HIDDEN];
    __shared__ float sc[8][IN_FEATS];

    const int t = threadIdx.x;
    {
        const float4* W1v = (const float4*)W1;
        float4* W1sv = (float4*)W1s;
#pragma unroll
        for (int i = 0; i < 4; ++i) W1sv[t + i * 256] = W1v[t + i * 256];
    }

    const int le = t >> 5;
    const int j  = t & 31;
    const int e = blockIdx.x * 8 + le;
    __syncthreads();

    if (e < n_edges) {
        const int s = src[e];
        const int d = dst[e];
        const float4* hs4 = (const float4*)(h + (size_t)s * IN_FEATS);
        const float4* hd4 = (const float4*)(h + (size_t)d * IN_FEATS);
        float4* sc4 = (float4*)sc[le];
        float4 a = hs4[j], b = hd4[j];
        sc4[j] = make_float4(a.x + b.x, a.y + b.y, a.z + b.z, a.w + b.w);
    }
    __syncthreads();

    if (e >= n_edges) return;

    float acc = b1[j];
    const float* scp = sc[le];
#pragma unroll
    for (int k = 0; k < IN_FEATS; ++k)
        acc = fmaf(scp[k], W1s[k * HIDDEN + j], acc);
    float hval = fmaxf(acc, 0.0f) * W2[j];

#pragma unroll
    for (int off = 16; off >= 1; off >>= 1)
        hval += __shfl_down(hval, off, 32);

    if (j == 0) out[e] = hval + b2[0];
}

extern "C" void kernel_launch(void* const* d_in, const int* in_sizes, int n_in,
                              void* d_out, int out_size, void* d_ws, size_t ws_size,
                              hipStream_t stream) {
    // setup_inputs() order: h, src, dst, W1, b1, W2, b2
    const float* h   = (const float*)d_in[0];
    const int*   src = (const int*)d_in[1];
    const int*   dst = (const int*)d_in[2];
    const float* W1  = (const float*)d_in[3];
    const float* b1  = (const float*)d_in[4];
    const float* W2  = (const float*)d_in[5];
    const float* b2  = (const float*)d_in[6];
    float* out = (float*)d_out;

    const int n_nodes = in_sizes[0] / IN_FEATS;   // 40000
    const int n_edges = in_sizes[1];              // 640000

    const size_t p_bytes = (size_t)n_nodes * HIDDEN * sizeof(unsigned short);  // 2.56 MB

    if (ws_size >= p_bytes) {
        unsigned short* p = (unsigned short*)d_ws;
        const int tiles = (n_nodes + 15) / 16;        // 2500
        node_proj_mfma<<<(tiles + 3) / 4, 256, 0, stream>>>(h, W1, b1, p, n_nodes);
        const int eblocks = (n_edges + 127) / 128;    // 128 edges per block
        edge_mlp_coop<<<eblocks, 256, 0, stream>>>(p, src, dst, W2, b2, out, n_edges);
    } else {
        fused_edge_kernel<<<(n_edges + 7) / 8, 256, 0, stream>>>(
            h, src, dst, W1, b1, W2, b2, out, n_edges);
    }
}

// Round 6
// 22.815 us; speedup vs baseline: 2.3210x; 1.0276x over previous
//
#include <hip/hip_runtime.h>
#include <hip/hip_bf16.h>

#define IN_FEATS 128
#define HIDDEN 32

typedef __attribute__((ext_vector_type(8))) short bf16x8;   // 8 bf16 (4 VGPRs)
typedef __attribute__((ext_vector_type(4))) float f32x4;
typedef _Float16 f16;
typedef __attribute__((ext_vector_type(2))) _Float16 f16x2;
typedef __attribute__((ext_vector_type(8))) _Float16 f16x8; // 16 B

// fp32 -> bf16 round-to-nearest-even (bit trick; NaN irrelevant for this data)
static __device__ __forceinline__ short f2bf(float f) {
    union { float f; unsigned u; } v;
    v.f = f;
    unsigned r = v.u + 0x7FFFu + ((v.u >> 16) & 1u);
    return (short)(r >> 16);
}

// Kernel 1 (MFMA): p[n] = fp16( h[n] @ W1 + 0.5*b1 )   [40000x128 @ 128x32]
// (b1 folded in half per endpoint: p[src]+p[dst] carries the full +b1.)
// Verified gfx950 16x16x32 bf16 layouts (learn_hip m89/m91):
//   A-frag: lane holds A[m=lane&15][k=(lane>>4)*8+i]; B-frag: B[k][n=lane&15]
//   D: lane holds D[row=(lane>>4)*4+r][col=lane&15]
__global__ __launch_bounds__(256) void node_proj_mfma(
    const float* __restrict__ h,
    const float* __restrict__ W1,
    const float* __restrict__ b1,
    f16* __restrict__ p,               // fp16 out
    int n_nodes) {
    const int t = threadIdx.x;
    const int lane = t & 63;
    const int wave = t >> 6;
    const int tile = blockIdx.x * 4 + wave;
    const int row0 = tile * 16;
    if (row0 >= n_nodes) return;

    const int lr = lane & 15;
    const int kg = lane >> 4;

    // B fragments from W1 (row-major [128][32]): 16 KB, L1/L2-resident.
    bf16x8 bfrag[2][4];
#pragma unroll
    for (int ct = 0; ct < 2; ++ct) {
#pragma unroll
        for (int ks = 0; ks < 4; ++ks) {
            const float* wp = W1 + (size_t)(ks * 32 + kg * 8) * HIDDEN + ct * 16 + lr;
#pragma unroll
            for (int i = 0; i < 8; ++i)
                bfrag[ct][ks][i] = f2bf(wp[(size_t)i * HIDDEN]);
        }
    }

    // A fragments from h; 8 consecutive floats per kstep = 2 float4.
    const float* hrow = h + (size_t)(row0 + lr) * IN_FEATS + kg * 8;
    bf16x8 afrag[4];
#pragma unroll
    for (int ks = 0; ks < 4; ++ks) {
        const float4 v0 = *(const float4*)(hrow + ks * 32);
        const float4 v1 = *(const float4*)(hrow + ks * 32 + 4);
        afrag[ks][0] = f2bf(v0.x);
        afrag[ks][1] = f2bf(v0.y);
        afrag[ks][2] = f2bf(v0.z);
        afrag[ks][3] = f2bf(v0.w);
        afrag[ks][4] = f2bf(v1.x);
        afrag[ks][5] = f2bf(v1.y);
        afrag[ks][6] = f2bf(v1.z);
        afrag[ks][7] = f2bf(v1.w);
    }

    // init acc with 0.5*b1[col] so the bias rides through the MFMA C-operand
    const float hb0 = 0.5f * b1[lr];
    const float hb1 = 0.5f * b1[16 + lr];
    f32x4 acc0 = {hb0, hb0, hb0, hb0};
    f32x4 acc1 = {hb1, hb1, hb1, hb1};
#pragma unroll
    for (int ks = 0; ks < 4; ++ks) {
        acc0 = __builtin_amdgcn_mfma_f32_16x16x32_bf16(afrag[ks], bfrag[0][ks], acc0, 0, 0, 0);
        acc1 = __builtin_amdgcn_mfma_f32_16x16x32_bf16(afrag[ks], bfrag[1][ks], acc1, 0, 0, 0);
    }

    // Store fp16: D[row=(kg*4+r)][col=ct*16+lr]
    f16* prow = p + (size_t)row0 * HIDDEN;
#pragma unroll
    for (int r = 0; r < 4; ++r) {
        prow[(size_t)(kg * 4 + r) * HIDDEN + lr]      = (f16)acc0[r];
        prow[(size_t)(kg * 4 + r) * HIDDEN + 16 + lr] = (f16)acc1[r];
    }
}

// Kernel 2: 4 lanes per edge, 4 consecutive edges per slot, packed fp16 math.
// Per edge: 2 x 16B row-gathers per lane-group (1 cache line per row), then
// v_pk_add_f16 + v_pk_max_f16 + v_dot2_f32_f16, 2-step shfl reduce.
__global__ __launch_bounds__(256) void edge_mlp_f16(
    const f16* __restrict__ p,     // fp16 [n_nodes][32], includes +b1/2
    const int* __restrict__ src,
    const int* __restrict__ dst,
    const float* __restrict__ W2,
    const float* __restrict__ b2,
    float* __restrict__ out,
    int n_edges) {
    const int t = threadIdx.x;
    const int q = t & 3;          // 8-unit slot within the 32-unit row
    const int slot = t >> 2;      // edge-group within block (0..63)

    // W2 slice for units q*8 .. q*8+7 as 4 half2 (converted once)
    const float4 w0 = ((const float4*)W2)[q * 2];
    const float4 w1 = ((const float4*)W2)[q * 2 + 1];
    f16x2 w2h[4];
    w2h[0] = f16x2{(f16)w0.x, (f16)w0.y};
    w2h[1] = f16x2{(f16)w0.z, (f16)w0.w};
    w2h[2] = f16x2{(f16)w1.x, (f16)w1.y};
    w2h[3] = f16x2{(f16)w1.z, (f16)w1.w};
    const float b2s = b2[0];
    const f16x2 zero2 = f16x2{(f16)0.0f, (f16)0.0f};

    const int e0 = (blockIdx.x * 64 + slot) * 4;
    if (e0 >= n_edges) return;

    if (e0 + 3 < n_edges) {
        const int4 s4 = *(const int4*)(src + e0);   // broadcast within group
        const int4 d4 = *(const int4*)(dst + e0);

        // 8 independent 16B gathers, all in flight before compute
        const f16x8 a0 = *(const f16x8*)(p + (size_t)s4.x * HIDDEN + q * 8);
        const f16x8 a1 = *(const f16x8*)(p + (size_t)s4.y * HIDDEN + q * 8);
        const f16x8 a2 = *(const f16x8*)(p + (size_t)s4.z * HIDDEN + q * 8);
        const f16x8 a3 = *(const f16x8*)(p + (size_t)s4.w * HIDDEN + q * 8);
        const f16x8 c0 = *(const f16x8*)(p + (size_t)d4.x * HIDDEN + q * 8);
        const f16x8 c1 = *(const f16x8*)(p + (size_t)d4.y * HIDDEN + q * 8);
        const f16x8 c2 = *(const f16x8*)(p + (size_t)d4.z * HIDDEN + q * 8);
        const f16x8 c3 = *(const f16x8*)(p + (size_t)d4.w * HIDDEN + q * 8);

        const f16x8 A[4] = {a0, a1, a2, a3};
        const f16x8 C[4] = {c0, c1, c2, c3};

        float res[4];
#pragma unroll
        for (int i = 0; i < 4; ++i) {
            float part = 0.0f;
#pragma unroll
            for (int j = 0; j < 4; ++j) {
                f16x2 av = f16x2{A[i][2 * j], A[i][2 * j + 1]};
                f16x2 cv = f16x2{C[i][2 * j], C[i][2 * j + 1]};
                f16x2 sum = av + cv;                              // v_pk_add_f16
                f16x2 rl = __builtin_elementwise_max(sum, zero2); // v_pk_max_f16
#if __has_builtin(__builtin_amdgcn_fdot2)
                part = __builtin_amdgcn_fdot2(rl, w2h[j], part, false);
#else
                part = fmaf((float)rl[0], (float)w2h[j][0], part);
                part = fmaf((float)rl[1], (float)w2h[j][1], part);
#endif
            }
            part += __shfl_xor(part, 1, 4);
            part += __shfl_xor(part, 2, 4);
            res[i] = part + b2s;
        }

        if (q == 0) {
            *(float4*)(out + e0) = make_float4(res[0], res[1], res[2], res[3]);
        }
    } else {
        // scalar tail (not hit for 640000 edges, kept for generality)
        for (int i = 0; i < 4 && e0 + i < n_edges; ++i) {
            const int s = src[e0 + i];
            const int d = dst[e0 + i];
            const f16x8 a = *(const f16x8*)(p + (size_t)s * HIDDEN + q * 8);
            const f16x8 c = *(const f16x8*)(p + (size_t)d * HIDDEN + q * 8);
            float part = 0.0f;
#pragma unroll
            for (int j = 0; j < 4; ++j) {
                float s0 = (float)a[2 * j] + (float)c[2 * j];
                float s1 = (float)a[2 * j + 1] + (float)c[2 * j + 1];
                part = fmaf(fmaxf(s0, 0.0f), (float)w2h[j][0], part);
                part = fmaf(fmaxf(s1, 0.0f), (float)w2h[j][1], part);
            }
            part += __shfl_xor(part, 1, 4);
            part += __shfl_xor(part, 2, 4);
            if (q == 0) out[e0 + i] = part + b2s;
        }
    }
}

// Fallback (only if ws too small for p): fused, correct, slower.
__global__ __launch_bounds__(256) void fused_edge_kernel(
    const float* __restrict__ h,
    const int* __restrict__ src,
    const int* __restrict__ dst,
    const float* __restrict__ W1,
    const float* __restrict__ b1,
    const float* __restrict__ W2,
    const float* __restrict__ b2,
    float* __restrict__ out,
    int n_edges) {
    __shared__ float W1s[IN_FEATS * HIDDEN];
    __shared__ float sc[8][IN_FEATS];

    const int t = threadIdx.x;
    {
        const float4* W1v = (const float4*)W1;
        float4* W1sv = (float4*)W1s;
#pragma unroll
        for (int i = 0; i < 4; ++i) W1sv[t + i * 256] = W1v[t + i * 256];
    }

    const int le = t >> 5;
    const int j  = t & 31;
    const int e = blockIdx.x * 8 + le;
    __syncthreads();

    if (e < n_edges) {
        const int s = src[e];
        const int d = dst[e];
        const float4* hs4 = (const float4*)(h + (size_t)s * IN_FEATS);
        const float4* hd4 = (const float4*)(h + (size_t)d * IN_FEATS);
        float4* sc4 = (float4*)sc[le];
        float4 a = hs4[j], b = hd4[j];
        sc4[j] = make_float4(a.x + b.x, a.y + b.y, a.z + b.z, a.w + b.w);
    }
    __syncthreads();

    if (e >= n_edges) return;

    float acc = b1[j];
    const float* scp = sc[le];
#pragma unroll
    for (int k = 0; k < IN_FEATS; ++k)
        acc = fmaf(scp[k], W1s[k * HIDDEN + j], acc);
    float hval = fmaxf(acc, 0.0f) * W2[j];

#pragma unroll
    for (int off = 16; off >= 1; off >>= 1)
        hval += __shfl_down(hval, off, 32);

    if (j == 0) out[e] = hval + b2[0];
}

extern "C" void kernel_launch(void* const* d_in, const int* in_sizes, int n_in,
                              void* d_out, int out_size, void* d_ws, size_t ws_size,
                              hipStream_t stream) {
    // setup_inputs() order: h, src, dst, W1, b1, W2, b2
    const float* h   = (const float*)d_in[0];
    const int*   src = (const int*)d_in[1];
    const int*   dst = (const int*)d_in[2];
    const float* W1  = (const float*)d_in[3];
    const float* b1  = (const float*)d_in[4];
    const float* W2  = (const float*)d_in[5];
    const float* b2  = (const float*)d_in[6];
    float* out = (float*)d_out;

    const int n_nodes = in_sizes[0] / IN_FEATS;   // 40000
    const int n_edges = in_sizes[1];              // 640000

    const size_t p_bytes = (size_t)n_nodes * HIDDEN * sizeof(f16);   // 2.56 MB

    if (ws_size >= p_bytes) {
        f16* p = (f16*)d_ws;
        const int tiles = (n_nodes + 15) / 16;        // 2500
        node_proj_mfma<<<(tiles + 3) / 4, 256, 0, stream>>>(h, W1, b1, p, n_nodes);
        const int eblocks = (n_edges + 255) / 256;    // 256 edges per block
        edge_mlp_f16<<<eblocks, 256, 0, stream>>>(p, src, dst, W2, b2, out, n_edges);
    } else {
        fused_edge_kernel<<<(n_edges + 7) / 8, 256, 0, stream>>>(
            h, src, dst, W1, b1, W2, b2, out, n_edges);
    }
}